// Round 1
// baseline (36435.822 us; speedup 1.0000x reference)
//
#include <hip/hip_runtime.h>

// Spiking LSTM (LIF gates), T=1024, N=32, I=H=1024, 4H=4096.
// Strategy: full float64 internal computation to reproduce the numpy
// reference's spike decisions exactly (binary outputs are flip-sensitive).
//   K0: zero state
//   K1: Whp[k][j] = (double)Wh[j][k]   (k-major f64 copy for coalesced reads)
//   K2: Gx[t,n,j] = sum_i X[t,n,i]*Wx[j,i] + bx[j] + bh[j]   (f64, chunked)
//   per step t: K3 (recurrent partial GEMM, k-split 8) ; K4 (LIF + c/h update)

#define NBATCH 32
#define HID    1024
#define FH     4096
#define TK     1024
#define TT     1024
#define TNH    (TT * NBATCH * HID)   // 33554432

// ---------------- K0: zero init ----------------
__global__ __launch_bounds__(256) void k_zero(double* __restrict__ p, int n) {
    int i = blockIdx.x * 256 + threadIdx.x;
    int stride = gridDim.x * 256;
    for (; i < n; i += stride) p[i] = 0.0;
}

// ---------------- K1: Wh transpose -> f64, k-major ----------------
__global__ __launch_bounds__(256) void k_prep(const float* __restrict__ Wh,
                                              double* __restrict__ Whp) {
    __shared__ float tile[64][33];
    int tid = threadIdx.x;
    int jt = blockIdx.x & 63;   // 64 j-tiles of 64
    int kt = blockIdx.x >> 6;   // 32 k-tiles of 32
    int j0 = jt * 64, k0 = kt * 32;
#pragma unroll
    for (int s = 0; s < 2; ++s) {
        int q = tid * 2 + s;            // 0..511 quads
        int jj = q >> 3, kq = q & 7;
        float4 f = *(const float4*)(Wh + (size_t)(j0 + jj) * TK + k0 + kq * 4);
        tile[jj][kq * 4 + 0] = f.x;
        tile[jj][kq * 4 + 1] = f.y;
        tile[jj][kq * 4 + 2] = f.z;
        tile[jj][kq * 4 + 3] = f.w;
    }
    __syncthreads();
#pragma unroll
    for (int r = 0; r < 8; ++r) {
        int lin = r * 256 + tid;        // 0..2047
        int jj2 = lin & 63, kk2 = lin >> 6;
        Whp[(size_t)(k0 + kk2) * FH + j0 + jj2] = (double)tile[jj2][kk2];
    }
}

// ---------------- K2: input GEMM (f64 accumulate) ----------------
// C tile 128(m) x 64(j), BK=16, 256 threads, acc 8x4 f64 per thread.
#define BK 16
__global__ __launch_bounds__(256) void k_xgemm(const float* __restrict__ X,
                                               const float* __restrict__ Wx,
                                               const float* __restrict__ bx,
                                               const float* __restrict__ bh,
                                               double* __restrict__ Gx) {
    __shared__ double Al[BK][130];
    __shared__ double Bl[BK][66];
    int tid = threadIdx.x;
    int j0 = blockIdx.x * 64;
    size_t m0 = (size_t)blockIdx.y * 128;

    double acc[8][4];
#pragma unroll
    for (int r = 0; r < 8; ++r)
#pragma unroll
        for (int c = 0; c < 4; ++c) acc[r][c] = 0.0;

    int mo4 = (tid & 15) * 4;      // a rows: mo4..+3 and 64+mo4..+3
    int jo4 = (tid >> 4) * 4;      // b cols
    int mm = tid >> 1, kh = (tid & 1) * 8;   // A staging
    int jj = tid >> 2, kq = (tid & 3) * 4;   // B staging

    for (int k0 = 0; k0 < TK; k0 += BK) {
        float4 fa0 = *(const float4*)(X + (m0 + mm) * TK + k0 + kh);
        float4 fa1 = *(const float4*)(X + (m0 + mm) * TK + k0 + kh + 4);
        float4 fb  = *(const float4*)(Wx + (size_t)(j0 + jj) * TK + k0 + kq);
        Al[kh + 0][mm] = fa0.x; Al[kh + 1][mm] = fa0.y;
        Al[kh + 2][mm] = fa0.z; Al[kh + 3][mm] = fa0.w;
        Al[kh + 4][mm] = fa1.x; Al[kh + 5][mm] = fa1.y;
        Al[kh + 6][mm] = fa1.z; Al[kh + 7][mm] = fa1.w;
        Bl[kq + 0][jj] = fb.x; Bl[kq + 1][jj] = fb.y;
        Bl[kq + 2][jj] = fb.z; Bl[kq + 3][jj] = fb.w;
        __syncthreads();
#pragma unroll
        for (int kk = 0; kk < BK; ++kk) {
            double a[8], b[4];
#pragma unroll
            for (int i = 0; i < 4; ++i) {
                a[i]     = Al[kk][mo4 + i];
                a[4 + i] = Al[kk][64 + mo4 + i];
                b[i]     = Bl[kk][jo4 + i];
            }
#pragma unroll
            for (int r = 0; r < 8; ++r)
#pragma unroll
                for (int c = 0; c < 4; ++c) acc[r][c] += a[r] * b[c];
        }
        __syncthreads();
    }

    double bsum[4];
#pragma unroll
    for (int c = 0; c < 4; ++c) {
        int j = j0 + jo4 + c;
        bsum[c] = (double)bx[j] + (double)bh[j];
    }
#pragma unroll
    for (int r = 0; r < 8; ++r) {
        int mloc = (r < 4) ? (mo4 + r) : (64 + mo4 + (r - 4));
        double* dst = Gx + (m0 + mloc) * FH + j0 + jo4;
#pragma unroll
        for (int c = 0; c < 4; ++c) dst[c] = acc[r][c] + bsum[c];
    }
}

// ---------------- K3: recurrent partial GEMM, one timestep ----------------
// 256 blocks: jb(32 slices of 128 j) x ks(8 slices of 128 k). All 32 n per block.
// part[ks][n][j] += sum_{k in slice} h[n][k] * Wh[j][k]
__global__ __launch_bounds__(256) void k_rec(const double* __restrict__ Whp,
                                             const double* __restrict__ hprev,
                                             double* __restrict__ part) {
    __shared__ double hlds[NBATCH * 128];   // [n][kk]
    int tid = threadIdx.x;
    int b = blockIdx.x;
    int jb = b >> 3;
    int ks = b & 7;
    int kbase = ks * 128;
    int j0 = jb * 128 + (tid & 31) * 4;
    int n0 = (tid >> 5) * 4;

#pragma unroll
    for (int r = 0; r < 16; ++r) {
        int lin = r * 256 + tid;            // 0..4095
        int n = lin >> 7, kk = lin & 127;
        hlds[lin] = hprev[(size_t)n * HID + kbase + kk];
    }
    __syncthreads();

    double acc[4][4];
#pragma unroll
    for (int a = 0; a < 4; ++a)
#pragma unroll
        for (int c = 0; c < 4; ++c) acc[a][c] = 0.0;

    const double* wp = Whp + (size_t)kbase * FH + j0;
#pragma unroll 2
    for (int kk = 0; kk < 128; ++kk) {
        double w0 = wp[0], w1 = wp[1], w2 = wp[2], w3 = wp[3];
        double h0 = hlds[(n0 + 0) * 128 + kk];
        double h1 = hlds[(n0 + 1) * 128 + kk];
        double h2 = hlds[(n0 + 2) * 128 + kk];
        double h3 = hlds[(n0 + 3) * 128 + kk];
        acc[0][0] += h0 * w0; acc[0][1] += h0 * w1; acc[0][2] += h0 * w2; acc[0][3] += h0 * w3;
        acc[1][0] += h1 * w0; acc[1][1] += h1 * w1; acc[1][2] += h1 * w2; acc[1][3] += h1 * w3;
        acc[2][0] += h2 * w0; acc[2][1] += h2 * w1; acc[2][2] += h2 * w2; acc[2][3] += h2 * w3;
        acc[3][0] += h3 * w0; acc[3][1] += h3 * w1; acc[3][2] += h3 * w2; acc[3][3] += h3 * w3;
        wp += FH;
    }

#pragma unroll
    for (int a = 0; a < 4; ++a) {
        double* dst = part + ((size_t)ks * NBATCH + n0 + a) * FH + j0;
        dst[0] = acc[a][0]; dst[1] = acc[a][1]; dst[2] = acc[a][2]; dst[3] = acc[a][3];
    }
}

// ---------------- K4: LIF + cell/hidden update ----------------
// 32768 threads: u = n*1024 + jH. split order of gates: i, o, f, c_state.
__global__ __launch_bounds__(256) void k_lif(const double* __restrict__ Gx,
                                             const double* __restrict__ part,
                                             double* __restrict__ vi_s,
                                             double* __restrict__ vo_s,
                                             double* __restrict__ vf_s,
                                             double* __restrict__ vcs_s,
                                             double* __restrict__ vct_s,
                                             double* __restrict__ c_s,
                                             double* __restrict__ hnext,
                                             float* __restrict__ out,
                                             int t, int tl) {
    int u = blockIdx.x * 256 + threadIdx.x;   // 0..32767
    int n = u >> 10, jH = u & 1023;
    size_t base = ((size_t)tl * NBATCH + n) * FH + jH;

    double g[4];
#pragma unroll
    for (int grp = 0; grp < 4; ++grp) {
        double s = Gx[base + grp * HID];
#pragma unroll
        for (int ks = 0; ks < 8; ++ks)
            s += part[((size_t)ks * NBATCH + n) * FH + grp * HID + jH];
        g[grp] = s;
    }

    // LIF: v = v + (x - v)/2 ; s = (v - 0.1 >= 0) ; v = (1-s)*v
    double v, si, so, sf, scs, sct;

    v = vi_s[u];  v = v + (g[0] - v) * 0.5;
    si = ((v - 0.1) >= 0.0) ? 1.0 : 0.0;  v = (1.0 - si) * v;  vi_s[u] = v;

    v = vf_s[u];  v = v + (g[2] - v) * 0.5;
    sf = ((v - 0.1) >= 0.0) ? 1.0 : 0.0;  v = (1.0 - sf) * v;  vf_s[u] = v;

    v = vo_s[u];  v = v + (g[1] - v) * 0.5;
    so = ((v - 0.1) >= 0.0) ? 1.0 : 0.0;  v = (1.0 - so) * v;  vo_s[u] = v;

    v = vcs_s[u]; v = v + (g[3] - v) * 0.5;
    scs = ((v - 0.1) >= 0.0) ? 1.0 : 0.0; v = (1.0 - scs) * v; vcs_s[u] = v;

    double c = c_s[u];
    c = sf * c + si * scs;
    c_s[u] = c;

    v = vct_s[u]; v = v + (c - v) * 0.5;
    sct = ((v - 0.1) >= 0.0) ? 1.0 : 0.0; v = (1.0 - sct) * v; vct_s[u] = v;

    double h = so * sct;
    hnext[u] = h;
    out[(size_t)t * (NBATCH * HID) + u] = (float)h;
    if (t == TT - 1) {
        out[(size_t)TNH + u] = (float)h;                 // h_t
        out[(size_t)TNH + NBATCH * HID + u] = (float)c;  // c_t
    }
}

extern "C" void kernel_launch(void* const* d_in, const int* in_sizes, int n_in,
                              void* d_out, int out_size, void* d_ws, size_t ws_size,
                              hipStream_t stream) {
    (void)in_sizes; (void)n_in; (void)out_size;
    const float* X  = (const float*)d_in[0];
    const float* Wx = (const float*)d_in[1];
    const float* bx = (const float*)d_in[2];
    const float* Wh = (const float*)d_in[3];
    const float* bh = (const float*)d_in[4];
    float* out = (float*)d_out;

    double* ws   = (double*)d_ws;
    double* Whp  = ws;                                   // 1024*4096 = 4,194,304
    double* part = Whp + (size_t)TK * FH;                // 8*32*4096 = 1,048,576
    double* st   = part + (size_t)8 * NBATCH * FH;       // states: 8 * 32768
    double* vi_s  = st;
    double* vo_s  = vi_s  + 32768;
    double* vf_s  = vo_s  + 32768;
    double* vcs_s = vf_s  + 32768;
    double* vct_s = vcs_s + 32768;
    double* c_s   = vct_s + 32768;
    double* hb0   = c_s   + 32768;
    double* hb1   = hb0   + 32768;
    double* Gx    = hb1   + 32768;

    // choose time-chunk so Gx (chunkT MB) fits in workspace
    size_t fixedB = ((size_t)TK * FH + (size_t)8 * NBATCH * FH + (size_t)8 * 32768) * 8;
    int ct = 8;
    for (int cand = 1024; cand >= 8; cand >>= 1) {
        if (fixedB + (size_t)cand * NBATCH * FH * 8 <= ws_size) { ct = cand; break; }
    }
    int nchunk = TT / ct;

    hipLaunchKernelGGL(k_zero, dim3(256), dim3(256), 0, stream, st, 8 * 32768);
    hipLaunchKernelGGL(k_prep, dim3(2048), dim3(256), 0, stream, Wh, Whp);

    for (int c = 0; c < nchunk; ++c) {
        const float* Xc = X + (size_t)c * ct * NBATCH * TK;
        hipLaunchKernelGGL(k_xgemm, dim3(64, (ct * NBATCH) / 128), dim3(256), 0, stream,
                           Xc, Wx, bx, bh, Gx);
        for (int tl = 0; tl < ct; ++tl) {
            int t = c * ct + tl;
            const double* hp = (t & 1) ? hb1 : hb0;
            double* hn = (t & 1) ? hb0 : hb1;
            hipLaunchKernelGGL(k_rec, dim3(256), dim3(256), 0, stream, Whp, hp, part);
            hipLaunchKernelGGL(k_lif, dim3(128), dim3(256), 0, stream, Gx, part,
                               vi_s, vo_s, vf_s, vcs_s, vct_s, c_s, hn, out, t, tl);
        }
    }
}